// Round 4
// baseline (136.714 us; speedup 1.0000x reference)
//
#include <hip/hip_runtime.h>

// Problem constants (fixed by reference: B=32,D=64,H=32,W=32,K=2048)
#define N_PIX 32768   // B*H*W
#define DIM   64
#define KCODE 2048

typedef __attribute__((ext_vector_type(8))) short bf16x8;   // 8 bf16 = 4 VGPR
typedef __attribute__((ext_vector_type(4))) float f32x4;    // MFMA C/D

// bf16 round-to-nearest-even (manual, deterministic)
__device__ inline unsigned short f2bf(float v) {
    unsigned int u = __float_as_uint(v);
    return (unsigned short)((u + 0x7FFFu + ((u >> 16) & 1u)) >> 16);
}
__device__ inline float bf2f(unsigned short b) {
    return __uint_as_float(((unsigned int)b) << 16);
}

// ---------------------------------------------------------------------------
// convert_b v2 (UNCHANGED): 16 threads/code, 128 blocks. One coalesced float4
// load per thread, split to 3 bf16 planes, e_sq via width-16 shfl butterfly.
// ---------------------------------------------------------------------------
__global__ __launch_bounds__(256)
void convert_b_kernel(const float* __restrict__ cb, unsigned short* __restrict__ Bg,
                      float* __restrict__ esq) {
    const int t   = blockIdx.x * 256 + threadIdx.x;   // 32768 threads
    const int n   = t >> 4;                           // code id 0..2047
    const int sub = t & 15;                           // 16 thr per code
    const int ntile = n >> 4, ni = n & 15;

    const float4 v = *(const float4*)(cb + (size_t)n * DIM + sub * 4);  // coalesced

    unsigned int h01, h23, m01, m23, l01, l23;
    {
        unsigned short h, m, l;
        float r1;
        h = f2bf(v.x); r1 = v.x - bf2f(h); m = f2bf(r1); l = f2bf(r1 - bf2f(m));
        h01 = h;       m01 = m;       l01 = l;
        h = f2bf(v.y); r1 = v.y - bf2f(h); m = f2bf(r1); l = f2bf(r1 - bf2f(m));
        h01 |= (unsigned int)h << 16; m01 |= (unsigned int)m << 16; l01 |= (unsigned int)l << 16;
        h = f2bf(v.z); r1 = v.z - bf2f(h); m = f2bf(r1); l = f2bf(r1 - bf2f(m));
        h23 = h;       m23 = m;       l23 = l;
        h = f2bf(v.w); r1 = v.w - bf2f(h); m = f2bf(r1); l = f2bf(r1 - bf2f(m));
        h23 |= (unsigned int)h << 16; m23 |= (unsigned int)m << 16; l23 |= (unsigned int)l << 16;
    }

    // e_sq: per-thread partial then width-16 butterfly (pairwise order)
    float s = (v.x * v.x + v.y * v.y) + (v.z * v.z + v.w * v.w);
#pragma unroll
    for (int mk = 1; mk < 16; mk <<= 1) s += __shfl_xor(s, mk, 16);
    if (sub == 0) esq[n] = s;

    // dst: unit (ntile, kb=sub>>1), inner offset ni*16 + (sub&1)*8  — layout
    // identical to r12's Bg (dist kernel is byte-compatible).
    char* outb = (char*)Bg;
    const size_t u = ((((size_t)ntile) * 8 + (sub >> 1)) << 8) + ni * 16 + (sub & 1) * 8;
    uint2 hw2 = {h01, h23}, mw2 = {m01, m23}, lw2 = {l01, l23};
    *(uint2*)(outb + u)          = hw2;               // plane h (stride 256 KB)
    *(uint2*)(outb + 262144 + u) = mw2;               // plane m
    *(uint2*)(outb + 524288 + u) = lw2;               // plane l
}

// MFMA pass with LITERAL plane indices (SROA lesson: no array[array[i]]).
#define DO_PASS(APL, BPL, B)                                                 \
    _Pragma("unroll") for (int ks = 0; ks < 2; ++ks)                         \
    _Pragma("unroll") for (int mt = 0; mt < 2; ++mt)                         \
        acc[mt] = __builtin_amdgcn_mfma_f32_16x16x32_bf16(                   \
            af[APL][mt][ks], B[BPL][ks], acc[mt], 0, 0, 0);

// Load one tile's 6 B-fragments straight from global (L2/L1-resident) into
// registers. lane*16 within a 1 KB fragment-major unit = perfectly coalesced
// global_load_dwordx4. Issue order = consumption order (plane 2 first).
#define GLOAD_B(DST, IT)                                                     \
  {                                                                          \
    const char* gb = bp0 + (size_t)(IT) * 2048;                              \
    DST[2][0] = *(const bf16x8*)(gb + 524288);                               \
    DST[2][1] = *(const bf16x8*)(gb + 524288 + 1024);                        \
    DST[0][0] = *(const bf16x8*)(gb);                                        \
    DST[0][1] = *(const bf16x8*)(gb + 1024);                                 \
    DST[1][0] = *(const bf16x8*)(gb + 262144);                               \
    DST[1][1] = *(const bf16x8*)(gb + 262144 + 1024);                        \
  }

// One iteration, NO barriers: 24 MFMAs on the register-resident tile BCUR,
// then (while results settle) prefetch tile J+2 into the just-consumed
// buffer (prefetch distance = 2 tiles ~ 1 full iteration >> L2 latency;
// compiler inserts the counted vmcnt before the first dependent MFMA).
#define ITER(J, BCUR, PRE)                                                   \
  {                                                                          \
    f32x4 acc[2];                                                            \
    acc[0] = f32x4{0.f, 0.f, 0.f, 0.f};                                      \
    acc[1] = f32x4{0.f, 0.f, 0.f, 0.f};                                      \
    __builtin_amdgcn_s_setprio(1);                                           \
    DO_PASS(0, 2, BCUR)                                                      \
    DO_PASS(2, 0, BCUR)                                                      \
    DO_PASS(1, 1, BCUR)                                                      \
    DO_PASS(0, 1, BCUR)                                                      \
    DO_PASS(1, 0, BCUR)                                                      \
    DO_PASS(0, 0, BCUR)                                                      \
    __builtin_amdgcn_s_setprio(0);                                           \
    if (PRE) GLOAD_B(BCUR, (J) + 2)                                          \
    const int n = wn * 512 + (J) * 16 + col;                                 \
    const float e = esqS[n];                                                 \
    _Pragma("unroll") for (int mt = 0; mt < 2; ++mt)                         \
    _Pragma("unroll") for (int r = 0; r < 4; ++r) {                          \
      float d = fmaf(-2.f, acc[mt][r], e);                                   \
      if (d < best[mt][r]) { best[mt][r] = d; bidx[mt][r] = n; }             \
    }                                                                        \
  }

// ---------------------------------------------------------------------------
// Fused dist+argmin+gather v5: v2's proven wave geometry (512 thr = 8 waves,
// wm x wn, 512 blocks, 2 blocks/CU) but B now flows global->register
// double-buffer directly — NO LDS ring, NO DMA, NO barriers in the main
// loop. Waves free-run; L1 (32 KB) absorbs the wm-pair duplicate reads
// (24 KB/iter working set). LDS = 24 KB A-staging + 8 KB esq only.
// ---------------------------------------------------------------------------
__global__ __launch_bounds__(512, 4)
void dist_fused_kernel(const float* __restrict__ laten,
                       const unsigned short* __restrict__ Bg,
                       const float* __restrict__ esq,
                       const float* __restrict__ cb,
                       float* __restrict__ out0, float* __restrict__ out1) {
    __shared__ __align__(16) char ring[24576];   // A staging; reduce scratch
    __shared__ float esqS[2048];                 // 8 KB

    const int tid  = threadIdx.x;
    const int lane = tid & 63;
    const int wave = tid >> 6;                   // 0..7
    const int wm   = wave & 1;                   // 32-px half
    const int wn   = wave >> 1;                  // 512-code quarter
    const int quad = lane >> 4, col = lane & 15;
    const int bx = blockIdx.x;
    const int bb = bx >> 4, hw0 = (bx & 15) * 64;   // 64 px contiguous in hw

    const char* BgB = (const char*)Bg;
    // per-wave B base: plane 0, group wn, tile 0, this lane's 16 B
    const char* bp0 = BgB + (size_t)(wn * 32) * 2048 + lane * 16;

    // ---- stage A into ring (24 KB): split 8 dims of pixel p ----
    {
        const int p = tid & 63, dg = tid >> 6;   // dg 0..7 = kb unit
        const float* srcA = laten + (size_t)bb * 65536 + (size_t)dg * 8192 + hw0 + p;
        const int mt = p >> 4, mi = p & 15;      // mtile 0..3
        alignas(16) unsigned short hv[8], mv[8], lv[8];
#pragma unroll
        for (int j = 0; j < 8; ++j) {
            float v = srcA[(size_t)j << 10];     // coalesced across p
            unsigned short h = f2bf(v);
            float r1 = v - bf2f(h);
            unsigned short m = f2bf(r1);
            unsigned short l = f2bf(r1 - bf2f(m));
            hv[j] = h; mv[j] = m; lv[j] = l;
        }
        int u = ((mt * 8 + dg) << 8) + mi * 16;
        *(uint4*)(ring + u)         = *(uint4*)hv;   // plane h (8 KB stride)
        *(uint4*)(ring + 8192 + u)  = *(uint4*)mv;   // plane m
        *(uint4*)(ring + 16384 + u) = *(uint4*)lv;   // plane l
    }
    // stage e_sq (4 floats/thread)
    *(float4*)(esqS + tid * 4) = *(const float4*)(esq + tid * 4);
    __syncthreads();

    // ---- A fragments -> VGPRs: wave's 32-px half (48 regs resident) ----
    bf16x8 af[3][2][2];
#pragma unroll
    for (int pl = 0; pl < 3; ++pl)
#pragma unroll
        for (int mt = 0; mt < 2; ++mt)
#pragma unroll
            for (int ks = 0; ks < 2; ++ks)
                af[pl][mt][ks] = *(const bf16x8*)(ring + pl * 8192
                    + (((wm * 2 + mt) * 8 + ks * 4 + quad) << 8) + col * 16);
    __syncthreads();   // af read complete; ring is dead until reduce scratch

    // ---- prologue: tiles 0,1 into the register double-buffer ----
    bf16x8 bfrA[3][2], bfrB[3][2];
    GLOAD_B(bfrA, 0)
    GLOAD_B(bfrB, 1)

    float best[2][4];
    int   bidx[2][4];
#pragma unroll
    for (int mt = 0; mt < 2; ++mt)
#pragma unroll
        for (int r = 0; r < 4; ++r) { best[mt][r] = 3.4e38f; bidx[mt][r] = 0; }

    // ---- main loop: barrier-free, register-pipelined, waves free-run ----
    for (int j = 0; j < 32; j += 2) {
        ITER(j,     bfrA, (j) + 2 < 32)
        ITER(j + 1, bfrB, (j) + 3 < 32)
    }

    // ---- reduce: shfl over 16 cols, then LDS over the 4 wn quarters ----
    float* redD = (float*)ring;              // [64][4]
    int*   redI = (int*)(ring + 1024);       // [64][4]
    int*   idxF = (int*)(ring + 2048);       // [64]
#pragma unroll
    for (int mt = 0; mt < 2; ++mt)
#pragma unroll
        for (int r = 0; r < 4; ++r) {
            float d = best[mt][r];
            int   i = bidx[mt][r];
#pragma unroll
            for (int m = 1; m < 16; m <<= 1) {
                float od = __shfl_xor(d, m, 16);
                int   oi = __shfl_xor(i, m, 16);
                if (od < d || (od == d && oi < i)) { d = od; i = oi; }
            }
            if (col == 0) {
                int row = wm * 32 + mt * 16 + quad * 4 + r;   // pixel 0..63
                redD[row * 4 + wn] = d;
                redI[row * 4 + wn] = i;
            }
        }
    __syncthreads();

    if (tid < 64) {
        float bd = redD[tid * 4]; int bi = redI[tid * 4];
#pragma unroll
        for (int w = 1; w < 4; ++w) {
            float d = redD[tid * 4 + w]; int i = redI[tid * 4 + w];
            if (d < bd || (d == bd && i < bi)) { bd = d; bi = i; }
        }
        out0[bx * 64 + tid] = (float)bi;
        idxF[tid] = bi;
    }
    __syncthreads();

    // ---- fused gather: 64 px x 64 dims from the ORIGINAL fp32 codebook ----
    const int p = tid & 63, dg = tid >> 6;           // dg: 8 dims each
    const int idx = idxF[p];
    const float4* srcr = (const float4*)(cb + ((size_t)idx << 6) + dg * 8);
    float* o = out1 + (size_t)bb * 65536 + (size_t)dg * 8192 + hw0 + p;
    float4 v0 = srcr[0], v1 = srcr[1];
    o[(size_t)0 << 10] = v0.x; o[(size_t)1 << 10] = v0.y;
    o[(size_t)2 << 10] = v0.z; o[(size_t)3 << 10] = v0.w;
    o[(size_t)4 << 10] = v1.x; o[(size_t)5 << 10] = v1.y;
    o[(size_t)6 << 10] = v1.z; o[(size_t)7 << 10] = v1.w;
}

// ---------------------------------------------------------------------------
extern "C" void kernel_launch(void* const* d_in, const int* in_sizes, int n_in,
                              void* d_out, int out_size, void* d_ws, size_t ws_size,
                              hipStream_t stream) {
    const float* laten = (const float*)d_in[0];   // (32,64,32,32) fp32
    const float* cb    = (const float*)d_in[1];   // (2048,64) fp32

    float* out0 = (float*)d_out;                  // indices as float, N_PIX
    float* out1 = (float*)d_out + N_PIX;          // quant_laten, 2M

    // ws layout: esq 8 KB | Bg 768 KB   (~776 KB total)
    float* esq = (float*)d_ws;
    unsigned short* Bg = (unsigned short*)(esq + 2048);

    convert_b_kernel<<<128, 256, 0, stream>>>(cb, Bg, esq);

    dist_fused_kernel<<<512, 512, 0, stream>>>(laten, Bg, esq, cb, out0, out1);
}

// Round 5
// 104.568 us; speedup vs baseline: 1.3074x; 1.3074x over previous
//
#include <hip/hip_runtime.h>

// Problem constants (fixed by reference: B=32,D=64,H=32,W=32,K=2048)
#define N_PIX 32768   // B*H*W
#define DIM   64
#define KCODE 2048

typedef __attribute__((ext_vector_type(8))) short bf16x8;   // 8 bf16 = 4 VGPR
typedef __attribute__((ext_vector_type(4))) float f32x4;    // MFMA C/D

// bf16 round-to-nearest-even (manual, deterministic)
__device__ inline unsigned short f2bf(float v) {
    unsigned int u = __float_as_uint(v);
    return (unsigned short)((u + 0x7FFFu + ((u >> 16) & 1u)) >> 16);
}
__device__ inline float bf2f(unsigned short b) {
    return __uint_as_float(((unsigned int)b) << 16);
}

// ---------------------------------------------------------------------------
// convert_b v2 (UNCHANGED): 16 threads/code, 128 blocks. One coalesced float4
// load per thread, split to 3 bf16 planes, e_sq via width-16 shfl butterfly.
// ---------------------------------------------------------------------------
__global__ __launch_bounds__(256)
void convert_b_kernel(const float* __restrict__ cb, unsigned short* __restrict__ Bg,
                      float* __restrict__ esq) {
    const int t   = blockIdx.x * 256 + threadIdx.x;   // 32768 threads
    const int n   = t >> 4;                           // code id 0..2047
    const int sub = t & 15;                           // 16 thr per code
    const int ntile = n >> 4, ni = n & 15;

    const float4 v = *(const float4*)(cb + (size_t)n * DIM + sub * 4);  // coalesced

    unsigned int h01, h23, m01, m23, l01, l23;
    {
        unsigned short h, m, l;
        float r1;
        h = f2bf(v.x); r1 = v.x - bf2f(h); m = f2bf(r1); l = f2bf(r1 - bf2f(m));
        h01 = h;       m01 = m;       l01 = l;
        h = f2bf(v.y); r1 = v.y - bf2f(h); m = f2bf(r1); l = f2bf(r1 - bf2f(m));
        h01 |= (unsigned int)h << 16; m01 |= (unsigned int)m << 16; l01 |= (unsigned int)l << 16;
        h = f2bf(v.z); r1 = v.z - bf2f(h); m = f2bf(r1); l = f2bf(r1 - bf2f(m));
        h23 = h;       m23 = m;       l23 = l;
        h = f2bf(v.w); r1 = v.w - bf2f(h); m = f2bf(r1); l = f2bf(r1 - bf2f(m));
        h23 |= (unsigned int)h << 16; m23 |= (unsigned int)m << 16; l23 |= (unsigned int)l << 16;
    }

    // e_sq: per-thread partial then width-16 butterfly (pairwise order)
    float s = (v.x * v.x + v.y * v.y) + (v.z * v.z + v.w * v.w);
#pragma unroll
    for (int mk = 1; mk < 16; mk <<= 1) s += __shfl_xor(s, mk, 16);
    if (sub == 0) esq[n] = s;

    // dst: unit (ntile, kb=sub>>1), inner offset ni*16 + (sub&1)*8  — layout
    // identical to r12's Bg (dist kernel is byte-compatible).
    char* outb = (char*)Bg;
    const size_t u = ((((size_t)ntile) * 8 + (sub >> 1)) << 8) + ni * 16 + (sub & 1) * 8;
    uint2 hw2 = {h01, h23}, mw2 = {m01, m23}, lw2 = {l01, l23};
    *(uint2*)(outb + u)          = hw2;               // plane h (stride 256 KB)
    *(uint2*)(outb + 262144 + u) = mw2;               // plane m
    *(uint2*)(outb + 524288 + u) = lw2;               // plane l
}

// MFMA pass with LITERAL plane indices (SROA lesson: no array[array[i]]).
#define DO_PASS(APL, BPL)                                                    \
    _Pragma("unroll") for (int ks = 0; ks < 2; ++ks)                         \
    _Pragma("unroll") for (int mt = 0; mt < 2; ++mt)                         \
        acc[mt] = __builtin_amdgcn_mfma_f32_16x16x32_bf16(                   \
            af[APL][mt][ks], bfr[BPL][ks], acc[mt], 0, 0, 0);

// In-place streaming reload of ONE B plane for tile JN, straight from global
// (Bg is L2-resident; lane*16 in a 1 KB fragment-major unit = coalesced
// global_load_dwordx4). Placed immediately after the plane's LAST consuming
// pass, so no second buffer is needed (only transient WAR renaming).
#define RELOAD(PL, JN)                                                       \
    if ((JN) < 32) {                                                         \
      const char* gb = bp0 + (size_t)(JN) * 2048 + (size_t)(PL) * 262144;    \
      bfr[PL][0] = *(const bf16x8*)(gb);                                     \
      bfr[PL][1] = *(const bf16x8*)(gb + 1024);                              \
    }

// One iteration, NO barriers, single B buffer. Pass order (and therefore
// accumulation rounding) identical to r12: hl, lh, mm, hm, mh, hh.
// B-plane last uses: B2 @ pass1, B1 @ pass4, B0 @ pass6 -> reload there.
#define ITER(J)                                                              \
  {                                                                          \
    f32x4 acc[2];                                                            \
    acc[0] = f32x4{0.f, 0.f, 0.f, 0.f};                                      \
    acc[1] = f32x4{0.f, 0.f, 0.f, 0.f};                                      \
    __builtin_amdgcn_s_setprio(1);                                           \
    DO_PASS(0, 2)                                                            \
    RELOAD(2, (J) + 1)                                                       \
    DO_PASS(2, 0)                                                            \
    DO_PASS(1, 1)                                                            \
    DO_PASS(0, 1)                                                            \
    RELOAD(1, (J) + 1)                                                       \
    DO_PASS(1, 0)                                                            \
    DO_PASS(0, 0)                                                            \
    RELOAD(0, (J) + 1)                                                       \
    __builtin_amdgcn_s_setprio(0);                                           \
    const int n = wn * 512 + (J) * 16 + col;                                 \
    const float e = esqS[n];                                                 \
    _Pragma("unroll") for (int mt = 0; mt < 2; ++mt)                         \
    _Pragma("unroll") for (int r = 0; r < 4; ++r) {                          \
      float d = fmaf(-2.f, acc[mt][r], e);                                   \
      if (d < best[mt][r]) { best[mt][r] = d; bidx[mt][r] = n; }             \
    }                                                                        \
  }

// ---------------------------------------------------------------------------
// Fused dist+argmin+gather v6: v2's proven geometry (512 thr = 8 waves,
// wm x wn, 512 blocks, 2 blocks/CU) + barrier-free global->register B path
// with a SINGLE bfr buffer and per-plane in-place streaming reloads (the
// v5 spill fix: no second buffer -> peak VGPR ~110-125 <= 128 cap).
// LDS = 24 KB A-staging + 8 KB esq only; no ring, no DMA, no loop barriers.
// L1 (32 KB) dedupes the wm-pair's identical B reads (24 KB/iter set).
// ---------------------------------------------------------------------------
__global__ __launch_bounds__(512, 4)
void dist_fused_kernel(const float* __restrict__ laten,
                       const unsigned short* __restrict__ Bg,
                       const float* __restrict__ esq,
                       const float* __restrict__ cb,
                       float* __restrict__ out0, float* __restrict__ out1) {
    __shared__ __align__(16) char ring[24576];   // A staging; reduce scratch
    __shared__ float esqS[2048];                 // 8 KB

    const int tid  = threadIdx.x;
    const int lane = tid & 63;
    const int wave = tid >> 6;                   // 0..7
    const int wm   = wave & 1;                   // 32-px half
    const int wn   = wave >> 1;                  // 512-code quarter
    const int quad = lane >> 4, col = lane & 15;
    const int bx = blockIdx.x;
    const int bb = bx >> 4, hw0 = (bx & 15) * 64;   // 64 px contiguous in hw

    const char* BgB = (const char*)Bg;
    // per-wave B base: plane 0, group wn, tile 0, this lane's 16 B
    const char* bp0 = BgB + (size_t)(wn * 32) * 2048 + lane * 16;

    // ---- stage A into ring (24 KB): split 8 dims of pixel p ----
    {
        const int p = tid & 63, dg = tid >> 6;   // dg 0..7 = kb unit
        const float* srcA = laten + (size_t)bb * 65536 + (size_t)dg * 8192 + hw0 + p;
        const int mt = p >> 4, mi = p & 15;      // mtile 0..3
        alignas(16) unsigned short hv[8], mv[8], lv[8];
#pragma unroll
        for (int j = 0; j < 8; ++j) {
            float v = srcA[(size_t)j << 10];     // coalesced across p
            unsigned short h = f2bf(v);
            float r1 = v - bf2f(h);
            unsigned short m = f2bf(r1);
            unsigned short l = f2bf(r1 - bf2f(m));
            hv[j] = h; mv[j] = m; lv[j] = l;
        }
        int u = ((mt * 8 + dg) << 8) + mi * 16;
        *(uint4*)(ring + u)         = *(uint4*)hv;   // plane h (8 KB stride)
        *(uint4*)(ring + 8192 + u)  = *(uint4*)mv;   // plane m
        *(uint4*)(ring + 16384 + u) = *(uint4*)lv;   // plane l
    }
    // stage e_sq (4 floats/thread)
    *(float4*)(esqS + tid * 4) = *(const float4*)(esq + tid * 4);
    __syncthreads();

    // ---- A fragments -> VGPRs: wave's 32-px half (48 regs resident) ----
    bf16x8 af[3][2][2];
#pragma unroll
    for (int pl = 0; pl < 3; ++pl)
#pragma unroll
        for (int mt = 0; mt < 2; ++mt)
#pragma unroll
            for (int ks = 0; ks < 2; ++ks)
                af[pl][mt][ks] = *(const bf16x8*)(ring + pl * 8192
                    + (((wm * 2 + mt) * 8 + ks * 4 + quad) << 8) + col * 16);
    __syncthreads();   // af reads done before ring is reused as scratch

    // ---- prologue: tile 0 into the single register buffer ----
    bf16x8 bfr[3][2];
    RELOAD(2, 0)
    RELOAD(0, 0)
    RELOAD(1, 0)

    float best[2][4];
    int   bidx[2][4];
#pragma unroll
    for (int mt = 0; mt < 2; ++mt)
#pragma unroll
        for (int r = 0; r < 4; ++r) { best[mt][r] = 3.4e38f; bidx[mt][r] = 0; }

    // ---- main loop: barrier-free, single-buffer streaming, free-running ----
    for (int j = 0; j < 32; ++j) ITER(j)

    // ---- reduce: shfl over 16 cols, then LDS over the 4 wn quarters ----
    float* redD = (float*)ring;              // [64][4]
    int*   redI = (int*)(ring + 1024);       // [64][4]
    int*   idxF = (int*)(ring + 2048);       // [64]
#pragma unroll
    for (int mt = 0; mt < 2; ++mt)
#pragma unroll
        for (int r = 0; r < 4; ++r) {
            float d = best[mt][r];
            int   i = bidx[mt][r];
#pragma unroll
            for (int m = 1; m < 16; m <<= 1) {
                float od = __shfl_xor(d, m, 16);
                int   oi = __shfl_xor(i, m, 16);
                if (od < d || (od == d && oi < i)) { d = od; i = oi; }
            }
            if (col == 0) {
                int row = wm * 32 + mt * 16 + quad * 4 + r;   // pixel 0..63
                redD[row * 4 + wn] = d;
                redI[row * 4 + wn] = i;
            }
        }
    __syncthreads();

    if (tid < 64) {
        float bd = redD[tid * 4]; int bi = redI[tid * 4];
#pragma unroll
        for (int w = 1; w < 4; ++w) {
            float d = redD[tid * 4 + w]; int i = redI[tid * 4 + w];
            if (d < bd || (d == bd && i < bi)) { bd = d; bi = i; }
        }
        out0[bx * 64 + tid] = (float)bi;
        idxF[tid] = bi;
    }
    __syncthreads();

    // ---- fused gather: 64 px x 64 dims from the ORIGINAL fp32 codebook ----
    const int p = tid & 63, dg = tid >> 6;           // dg: 8 dims each
    const int idx = idxF[p];
    const float4* srcr = (const float4*)(cb + ((size_t)idx << 6) + dg * 8);
    float* o = out1 + (size_t)bb * 65536 + (size_t)dg * 8192 + hw0 + p;
    float4 v0 = srcr[0], v1 = srcr[1];
    o[(size_t)0 << 10] = v0.x; o[(size_t)1 << 10] = v0.y;
    o[(size_t)2 << 10] = v0.z; o[(size_t)3 << 10] = v0.w;
    o[(size_t)4 << 10] = v1.x; o[(size_t)5 << 10] = v1.y;
    o[(size_t)6 << 10] = v1.z; o[(size_t)7 << 10] = v1.w;
}

// ---------------------------------------------------------------------------
extern "C" void kernel_launch(void* const* d_in, const int* in_sizes, int n_in,
                              void* d_out, int out_size, void* d_ws, size_t ws_size,
                              hipStream_t stream) {
    const float* laten = (const float*)d_in[0];   // (32,64,32,32) fp32
    const float* cb    = (const float*)d_in[1];   // (2048,64) fp32

    float* out0 = (float*)d_out;                  // indices as float, N_PIX
    float* out1 = (float*)d_out + N_PIX;          // quant_laten, 2M

    // ws layout: esq 8 KB | Bg 768 KB   (~776 KB total)
    float* esq = (float*)d_ws;
    unsigned short* Bg = (unsigned short*)(esq + 2048);

    convert_b_kernel<<<128, 256, 0, stream>>>(cb, Bg, esq);

    dist_fused_kernel<<<512, 512, 0, stream>>>(laten, Bg, esq, cb, out0, out1);
}

// Round 6
// 102.854 us; speedup vs baseline: 1.3292x; 1.0167x over previous
//
#include <hip/hip_runtime.h>

// Problem constants (fixed by reference: B=32,D=64,H=32,W=32,K=2048)
#define N_PIX 32768   // B*H*W
#define DIM   64
#define KCODE 2048

typedef __attribute__((ext_vector_type(8))) short bf16x8;   // 8 bf16 = 4 VGPR
typedef __attribute__((ext_vector_type(4))) float f32x4;    // MFMA C/D

// bf16 round-to-nearest-even (manual, deterministic)
__device__ inline unsigned short f2bf(float v) {
    unsigned int u = __float_as_uint(v);
    return (unsigned short)((u + 0x7FFFu + ((u >> 16) & 1u)) >> 16);
}
__device__ inline float bf2f(unsigned short b) {
    return __uint_as_float(((unsigned int)b) << 16);
}

// ---------------------------------------------------------------------------
// convert_b v2 (UNCHANGED): 16 threads/code, 128 blocks. One coalesced float4
// load per thread, split to 3 bf16 planes, e_sq via width-16 shfl butterfly.
// ---------------------------------------------------------------------------
__global__ __launch_bounds__(256)
void convert_b_kernel(const float* __restrict__ cb, unsigned short* __restrict__ Bg,
                      float* __restrict__ esq) {
    const int t   = blockIdx.x * 256 + threadIdx.x;   // 32768 threads
    const int n   = t >> 4;                           // code id 0..2047
    const int sub = t & 15;                           // 16 thr per code
    const int ntile = n >> 4, ni = n & 15;

    const float4 v = *(const float4*)(cb + (size_t)n * DIM + sub * 4);  // coalesced

    unsigned int h01, h23, m01, m23, l01, l23;
    {
        unsigned short h, m, l;
        float r1;
        h = f2bf(v.x); r1 = v.x - bf2f(h); m = f2bf(r1); l = f2bf(r1 - bf2f(m));
        h01 = h;       m01 = m;       l01 = l;
        h = f2bf(v.y); r1 = v.y - bf2f(h); m = f2bf(r1); l = f2bf(r1 - bf2f(m));
        h01 |= (unsigned int)h << 16; m01 |= (unsigned int)m << 16; l01 |= (unsigned int)l << 16;
        h = f2bf(v.z); r1 = v.z - bf2f(h); m = f2bf(r1); l = f2bf(r1 - bf2f(m));
        h23 = h;       m23 = m;       l23 = l;
        h = f2bf(v.w); r1 = v.w - bf2f(h); m = f2bf(r1); l = f2bf(r1 - bf2f(m));
        h23 |= (unsigned int)h << 16; m23 |= (unsigned int)m << 16; l23 |= (unsigned int)l << 16;
    }

    // e_sq: per-thread partial then width-16 butterfly (pairwise order)
    float s = (v.x * v.x + v.y * v.y) + (v.z * v.z + v.w * v.w);
#pragma unroll
    for (int mk = 1; mk < 16; mk <<= 1) s += __shfl_xor(s, mk, 16);
    if (sub == 0) esq[n] = s;

    // dst: unit (ntile, kb=sub>>1), inner offset ni*16 + (sub&1)*8  — layout
    // identical to r12's Bg (dist kernel is byte-compatible).
    char* outb = (char*)Bg;
    const size_t u = ((((size_t)ntile) * 8 + (sub >> 1)) << 8) + ni * 16 + (sub & 1) * 8;
    uint2 hw2 = {h01, h23}, mw2 = {m01, m23}, lw2 = {l01, l23};
    *(uint2*)(outb + u)          = hw2;               // plane h (stride 256 KB)
    *(uint2*)(outb + 262144 + u) = mw2;               // plane m
    *(uint2*)(outb + 524288 + u) = lw2;               // plane l
}

// MFMA pass: 4 mtiles x 2 ks = 8 MFMAs, literal plane indices (SROA-safe).
#define DO_PASS(APL, BPL)                                                    \
    _Pragma("unroll") for (int ks = 0; ks < 2; ++ks)                         \
    _Pragma("unroll") for (int mt = 0; mt < 4; ++mt)                         \
        acc[mt] = __builtin_amdgcn_mfma_f32_16x16x32_bf16(                   \
            af[APL][mt][ks], bfr[BPL][ks], acc[mt], 0, 0, 0);

// In-place streaming reload of ONE B plane for tile JN, straight from global
// (Bg is L2-resident; lane*16 in a 1 KB fragment-major unit = coalesced
// global_load_dwordx4). Placed immediately after the plane's LAST consuming
// pass, so no second buffer is needed (only transient WAR renaming).
#define RELOAD(PL, JN)                                                       \
    if ((JN) < 32) {                                                         \
      const char* gb = bp0 + (size_t)(JN) * 2048 + (size_t)(PL) * 262144;    \
      bfr[PL][0] = *(const bf16x8*)(gb);                                     \
      bfr[PL][1] = *(const bf16x8*)(gb + 1024);                              \
    }

// One iteration, NO barriers, single B buffer, 48 MFMAs (64 px x 16 codes).
// Pass order (and therefore accumulation rounding) identical to r12:
// hl, lh, mm, hm, mh, hh. B-plane last uses: B2 @ pass1, B1 @ pass4,
// B0 @ pass6 -> in-place reload right after each.
#define ITER(J)                                                              \
  {                                                                          \
    f32x4 acc[4];                                                            \
    acc[0] = f32x4{0.f, 0.f, 0.f, 0.f};                                      \
    acc[1] = f32x4{0.f, 0.f, 0.f, 0.f};                                      \
    acc[2] = f32x4{0.f, 0.f, 0.f, 0.f};                                      \
    acc[3] = f32x4{0.f, 0.f, 0.f, 0.f};                                      \
    __builtin_amdgcn_s_setprio(1);                                           \
    DO_PASS(0, 2)                                                            \
    RELOAD(2, (J) + 1)                                                       \
    DO_PASS(2, 0)                                                            \
    DO_PASS(1, 1)                                                            \
    DO_PASS(0, 1)                                                            \
    RELOAD(1, (J) + 1)                                                       \
    DO_PASS(1, 0)                                                            \
    DO_PASS(0, 0)                                                            \
    RELOAD(0, (J) + 1)                                                       \
    __builtin_amdgcn_s_setprio(0);                                           \
    const int n = wn * 512 + (J) * 16 + col;                                 \
    const float e = esqS[n];                                                 \
    _Pragma("unroll") for (int mt = 0; mt < 4; ++mt)                         \
    _Pragma("unroll") for (int r = 0; r < 4; ++r) {                          \
      float d = fmaf(-2.f, acc[mt][r], e);                                   \
      if (d < best[mt][r]) { best[mt][r] = d; bidx[mt][r] = n; }             \
    }                                                                        \
  }

// ---------------------------------------------------------------------------
// Fused dist+argmin+gather v7: v6's barrier-free global->register streaming
// loop grafted onto the 256-thread geometry — 4 waves, EACH wave owns all
// 64 px (4 mtiles) x its own 512-code strip (ntile = wn*32 + it, addressing
// identical to v6). Doubles B-reuse: 48 MFMAs per 6 KB of B per wave-iter,
// so per-CU L1-return traffic halves (the round-5 diagnosis). No LDS ring,
// no DMA, no loop barriers (v4's failure modes). VGPR ~190 <= 256 cap
// (launch_bounds 256,2): no spills, 2 waves/SIMD free-running.
// ---------------------------------------------------------------------------
__global__ __launch_bounds__(256, 2)
void dist_fused_kernel(const float* __restrict__ laten,
                       const unsigned short* __restrict__ Bg,
                       const float* __restrict__ esq,
                       const float* __restrict__ cb,
                       float* __restrict__ out0, float* __restrict__ out1) {
    __shared__ __align__(16) char ring[24576];   // A staging; reduce scratch
    __shared__ float esqS[2048];                 // 8 KB

    const int tid  = threadIdx.x;
    const int lane = tid & 63;
    const int wn   = tid >> 6;                   // wave 0..3 = 512-code strip
    const int quad = lane >> 4, col = lane & 15;
    const int bx = blockIdx.x;
    const int bb = bx >> 4, hw0 = (bx & 15) * 64;   // 64 px contiguous in hw

    const char* BgB = (const char*)Bg;
    // per-wave B base: plane 0, strip start ntile = wn*32, this lane's 16 B
    const char* bp0 = BgB + (size_t)(wn * 32) * 2048 + lane * 16;

    // ---- stage A into ring (24 KB): thread covers px p, 16 dims ----
    {
        const int p = tid & 63, dgp = tid >> 6;  // dgp 0..3 -> dg pairs
        const int mt = p >> 4, mi = p & 15;      // mtile 0..3
#pragma unroll
        for (int dd = 0; dd < 2; ++dd) {
            const int dg = dgp * 2 + dd;         // kb unit 0..7
            const float* srcA = laten + (size_t)bb * 65536 + (size_t)dg * 8192 + hw0 + p;
            alignas(16) unsigned short hv[8], mv[8], lv[8];
#pragma unroll
            for (int j = 0; j < 8; ++j) {
                float v = srcA[(size_t)j << 10]; // coalesced across p
                unsigned short h = f2bf(v);
                float r1 = v - bf2f(h);
                unsigned short m = f2bf(r1);
                unsigned short l = f2bf(r1 - bf2f(m));
                hv[j] = h; mv[j] = m; lv[j] = l;
            }
            int u = ((mt * 8 + dg) << 8) + mi * 16;
            *(uint4*)(ring + u)         = *(uint4*)hv;   // plane h (8 KB stride)
            *(uint4*)(ring + 8192 + u)  = *(uint4*)mv;   // plane m
            *(uint4*)(ring + 16384 + u) = *(uint4*)lv;   // plane l
        }
    }
    // stage e_sq (8 floats/thread, 256 threads -> 2048 floats)
    *(float4*)(esqS + tid * 8)     = *(const float4*)(esq + tid * 8);
    *(float4*)(esqS + tid * 8 + 4) = *(const float4*)(esq + tid * 8 + 4);
    __syncthreads();

    // ---- A fragments -> regs: ALL 4 mtiles per wave (96 regs resident) ----
    bf16x8 af[3][4][2];
#pragma unroll
    for (int pl = 0; pl < 3; ++pl)
#pragma unroll
        for (int mt = 0; mt < 4; ++mt)
#pragma unroll
            for (int ks = 0; ks < 2; ++ks)
                af[pl][mt][ks] = *(const bf16x8*)(ring + pl * 8192
                    + ((mt * 8 + ks * 4 + quad) << 8) + col * 16);
    __syncthreads();   // af reads done before ring is reused as scratch

    // ---- prologue: tile 0 into the single register buffer ----
    bf16x8 bfr[3][2];
    RELOAD(2, 0)
    RELOAD(0, 0)
    RELOAD(1, 0)

    float best[4][4];
    int   bidx[4][4];
#pragma unroll
    for (int mt = 0; mt < 4; ++mt)
#pragma unroll
        for (int r = 0; r < 4; ++r) { best[mt][r] = 3.4e38f; bidx[mt][r] = 0; }

    // ---- main loop: barrier-free, single-buffer streaming, free-running ----
    for (int j = 0; j < 32; ++j) ITER(j)

    // ---- reduce: shfl over 16 cols, then LDS over the 4 wn strips ----
    float* redD = (float*)ring;              // [64][4]
    int*   redI = (int*)(ring + 1024);       // [64][4]
    int*   idxF = (int*)(ring + 2048);       // [64]
#pragma unroll
    for (int mt = 0; mt < 4; ++mt)
#pragma unroll
        for (int r = 0; r < 4; ++r) {
            float d = best[mt][r];
            int   i = bidx[mt][r];
#pragma unroll
            for (int m = 1; m < 16; m <<= 1) {
                float od = __shfl_xor(d, m, 16);
                int   oi = __shfl_xor(i, m, 16);
                if (od < d || (od == d && oi < i)) { d = od; i = oi; }
            }
            if (col == 0) {
                int row = mt * 16 + quad * 4 + r;     // pixel 0..63
                redD[row * 4 + wn] = d;
                redI[row * 4 + wn] = i;
            }
        }
    __syncthreads();

    if (tid < 64) {
        float bd = redD[tid * 4]; int bi = redI[tid * 4];
#pragma unroll
        for (int w = 1; w < 4; ++w) {
            float d = redD[tid * 4 + w]; int i = redI[tid * 4 + w];
            if (d < bd || (d == bd && i < bi)) { bd = d; bi = i; }
        }
        out0[bx * 64 + tid] = (float)bi;
        idxF[tid] = bi;
    }
    __syncthreads();

    // ---- fused gather: 64 px x 64 dims from the ORIGINAL fp32 codebook ----
    const int p = tid & 63, dgp = tid >> 6;          // dgp: 16 dims each
    const int idx = idxF[p];
    const float4* srcr = (const float4*)(cb + ((size_t)idx << 6) + dgp * 16);
    float* o = out1 + (size_t)bb * 65536 + (size_t)dgp * 16384 + hw0 + p;
    float4 v0 = srcr[0], v1 = srcr[1], v2 = srcr[2], v3 = srcr[3];
    o[(size_t)0  << 10] = v0.x; o[(size_t)1  << 10] = v0.y;
    o[(size_t)2  << 10] = v0.z; o[(size_t)3  << 10] = v0.w;
    o[(size_t)4  << 10] = v1.x; o[(size_t)5  << 10] = v1.y;
    o[(size_t)6  << 10] = v1.z; o[(size_t)7  << 10] = v1.w;
    o[(size_t)8  << 10] = v2.x; o[(size_t)9  << 10] = v2.y;
    o[(size_t)10 << 10] = v2.z; o[(size_t)11 << 10] = v2.w;
    o[(size_t)12 << 10] = v3.x; o[(size_t)13 << 10] = v3.y;
    o[(size_t)14 << 10] = v3.z; o[(size_t)15 << 10] = v3.w;
}

// ---------------------------------------------------------------------------
extern "C" void kernel_launch(void* const* d_in, const int* in_sizes, int n_in,
                              void* d_out, int out_size, void* d_ws, size_t ws_size,
                              hipStream_t stream) {
    const float* laten = (const float*)d_in[0];   // (32,64,32,32) fp32
    const float* cb    = (const float*)d_in[1];   // (2048,64) fp32

    float* out0 = (float*)d_out;                  // indices as float, N_PIX
    float* out1 = (float*)d_out + N_PIX;          // quant_laten, 2M

    // ws layout: esq 8 KB | Bg 768 KB   (~776 KB total)
    float* esq = (float*)d_ws;
    unsigned short* Bg = (unsigned short*)(esq + 2048);

    convert_b_kernel<<<128, 256, 0, stream>>>(cb, Bg, esq);

    dist_fused_kernel<<<512, 256, 0, stream>>>(laten, Bg, esq, cb, out0, out1);
}